// Round 13
// baseline (640.795 us; speedup 1.0000x reference)
//
#include <hip/hip_runtime.h>
#include <hip/hip_bf16.h>
#include <cstdint>

// Problem constants
#define IMGE    384
#define XROWS   51              // LDS rows (need up to row 50 = 16*2+15+3)
#define XROWB   (XROWS * 640)   // 32640 bytes (320 bf16 cols, 640 B/row)
#define BLOB_OFF 256

using bf16x8 = short  __attribute__((ext_vector_type(8)));
using f32x4  = float  __attribute__((ext_vector_type(4)));

__device__ __forceinline__ unsigned int f2bf(float f) {
  unsigned int u = __builtin_bit_cast(unsigned int, f);
  u += 0x7FFFu + ((u >> 16) & 1u);          // round-to-nearest-even
  return u >> 16;
}

#define MF(a, b, c) __builtin_amdgcn_mfma_f32_16x16x32_bf16(a, b, c, 0, 0, 0)

// ---------------------------------------------------------------------------
// Prep: repack conv weights (fp32, [256][1][k][300]) into bf16 fragment-order
// blob: byte = ((kappa*768 + F)*32 + e')*2, kappa = j*10+kk, e = kk*32+e'.
// ---------------------------------------------------------------------------
__global__ __launch_bounds__(256) void prep_weights(
    const float* __restrict__ w2, const float* __restrict__ w3,
    const float* __restrict__ w4, unsigned short* __restrict__ blob)
{
  int kappa = blockIdx.x;                       // 0..39
  int fq = blockIdx.y * 256 + threadIdx.x;      // F*4 + q, 0..3071
  int F = fq >> 2;
  int q = fq & 3;
  int j = kappa / 10, kk = kappa - 10 * j;
  int ch = F >> 8, f = F & 255;
  int k = ch + 2;
  const float* w = (ch == 0) ? w2 : (ch == 1 ? w3 : w4);

  bf16x8 pv;
  if (j < k) {
    const float* src = w + (size_t)(f * k + j) * 300;
    #pragma unroll
    for (int i = 0; i < 8; i++) {
      int e = kk * 32 + q * 8 + i;
      pv[i] = (e < 300) ? (short)f2bf(src[e]) : (short)0;
    }
  } else {
    #pragma unroll
    for (int i = 0; i < 8; i++) pv[i] = 0;
  }
  unsigned short* dst = blob + (size_t)(kappa * 768 + F) * 32 + q * 8;
  *(bf16x8*)dst = pv;
}

// ---------------------------------------------------------------------------
// GEMM inner loop: 4 N-tiles, compile-time tap counts K0..K3, fully unrolled.
// B: depth-BD prefetch through a 4-slot circular register file.
// A (LDS): depth-1 through a 2-slot file.
// rotk (0..9, wave-uniform) rotates the kk stream (sum over kappa invariant).
// All slot indices compile-time (no runtime-indexed ext_vector arrays).
// ---------------------------------------------------------------------------
template<int K0, int K1, int K2, int K3, int BD>
__device__ __forceinline__ void gemm4(
    const char* Xs, const char* bb0, const char* bb1,
    const char* bb2, const char* bb3,
    int l15, int hi, int rotk, f32x4 (&acc)[4][3])
{
  constexpr int KA = K0 > K1 ? K0 : K1;
  constexpr int KB = K2 > K3 ? K2 : K3;
  constexpr int KM = KA > KB ? KA : KB;
  constexpr int T  = KM * 10;

  bf16x8 Ap[2][3];
  bf16x8 Bp[4][4];

  const int hx = (hi * 16);

#define KKE(KK) ({ int kke_ = (KK) + rotk; if (kke_ >= 10) kke_ -= 10; kke_; })

#define ISSUE_A(TT, SL) {                                                \
    const int j_ = (TT) / 10, kk_ = (TT) - 10 * ((TT) / 10);             \
    const int kke_ = KKE(kk_);                                           \
    _Pragma("unroll")                                                    \
    for (int m_ = 0; m_ < 3; m_++) {                                     \
      int row_ = m_ * 16 + l15 + j_;                                     \
      int cc_  = (kke_ * 64 + hx) ^ ((row_ & 7) << 4);                   \
      Ap[SL][m_] = *(const bf16x8*)(Xs + (row_ * 640 + cc_));            \
    } }

#define ISSUE_B(TT, SL) {                                                \
    const int j_ = (TT) / 10, kk_ = (TT) - 10 * ((TT) / 10);             \
    const int kke_ = KKE(kk_);                                           \
    const int ko_ = (j_ * 10 + kke_) * 49152;                            \
    if (j_ < K0) Bp[SL][0] = *(const bf16x8*)(bb0 + ko_);                \
    if (j_ < K1) Bp[SL][1] = *(const bf16x8*)(bb1 + ko_);                \
    if (j_ < K2) Bp[SL][2] = *(const bf16x8*)(bb2 + ko_);                \
    if (j_ < K3) Bp[SL][3] = *(const bf16x8*)(bb3 + ko_); }

  // prologue: A depth 1, B depth BD
  ISSUE_A(0, 0)
  #pragma unroll
  for (int pb = 0; pb < BD; pb++) { ISSUE_B(pb, pb & 3) }

  #pragma unroll
  for (int t = 0; t < T; ++t) {
    const int j = t / 10;
    if (t + 1 < T)  { ISSUE_A(t + 1, (t + 1) & 1) }
    if (t + BD < T) { ISSUE_B(t + BD, (t + BD) & 3) }
    __builtin_amdgcn_s_setprio(1);
    {
      const int sa = t & 1, sbt = t & 3;
      if (j < K0) { acc[0][0] = MF(Ap[sa][0], Bp[sbt][0], acc[0][0]);
                    acc[0][1] = MF(Ap[sa][1], Bp[sbt][0], acc[0][1]);
                    acc[0][2] = MF(Ap[sa][2], Bp[sbt][0], acc[0][2]); }
      if (j < K1) { acc[1][0] = MF(Ap[sa][0], Bp[sbt][1], acc[1][0]);
                    acc[1][1] = MF(Ap[sa][1], Bp[sbt][1], acc[1][1]);
                    acc[1][2] = MF(Ap[sa][2], Bp[sbt][1], acc[1][2]); }
      if (j < K2) { acc[2][0] = MF(Ap[sa][0], Bp[sbt][2], acc[2][0]);
                    acc[2][1] = MF(Ap[sa][1], Bp[sbt][2], acc[2][1]);
                    acc[2][2] = MF(Ap[sa][2], Bp[sbt][2], acc[2][2]); }
      if (j < K3) { acc[3][0] = MF(Ap[sa][0], Bp[sbt][3], acc[3][0]);
                    acc[3][1] = MF(Ap[sa][1], Bp[sbt][3], acc[3][1]);
                    acc[3][2] = MF(Ap[sa][2], Bp[sbt][3], acc[3][2]); }
    }
    __builtin_amdgcn_s_setprio(0);
  }
#undef ISSUE_A
#undef ISSUE_B
#undef KKE
}

// ---------------------------------------------------------------------------
// Main (templated ablation variant): 768 thr (12 waves), ONE sentence/block.
// Wave owns 4 channel-balanced N-tiles. BD = B prefetch depth; ROT = kappa
// stream rotation. Sid = sidBase + blockIdx.x.
// ---------------------------------------------------------------------------
template<int BD, bool ROT>
__global__ __launch_bounds__(768, 3) void main_conv_t(
    const int*  __restrict__ sb,   const float* __restrict__ W,
    const float* __restrict__ b2,  const float* __restrict__ b3,
    const float* __restrict__ b4,  const unsigned short* __restrict__ blob,
    float* __restrict__ out, float* __restrict__ nrm, int sidBase)
{
  __shared__ __align__(128) char X[XROWB];      // 32640 B
  __shared__ float wss[12];
  const int tid = threadIdx.x;
  const int wv  = tid >> 6;                     // 0..11
  const int l   = tid & 63;
  const int l15 = l & 15;
  const int hi  = l >> 4;
  const int Sid = sidBase + blockIdx.x;         // sentence id 0..4095

  // zero LDS (covers e in [300,320) pads and rows 40..50)
  for (int off = tid * 16; off < XROWB; off += 768 * 16)
    *(f32x4*)(X + off) = f32x4{0.f, 0.f, 0.f, 0.f};
  __syncthreads();

  // gather embeddings: 40 rows x 75 float4 chunks
  for (int idx = tid; idx < 3000; idx += 768) {
    int r  = idx / 75;
    int c4 = idx - r * 75;
    int tok = sb[Sid * 40 + r];
    float4 wvv = *(const float4*)(W + (size_t)tok * 300 + c4 * 4);
    uint2 pk;
    pk.x = f2bf(wvv.x) | (f2bf(wvv.y) << 16);
    pk.y = f2bf(wvv.z) | (f2bf(wvv.w) << 16);
    int off = r * 640 + ((c4 * 8) ^ ((r & 7) << 4));
    *(uint2*)(X + off) = pk;
  }
  __syncthreads();

  f32x4 acc[4][3];
  #pragma unroll
  for (int n = 0; n < 4; n++)
    #pragma unroll
    for (int m = 0; m < 3; m++)
      acc[n][m] = f32x4{0.f, 0.f, 0.f, 0.f};

  // tile assignment (wave-uniform)
  int Fb[4], chn[4];
  if (wv < 8) {
    Fb[0] = wv * 32;       Fb[1] = wv * 32 + 16;
    Fb[2] = 512 + wv * 32; Fb[3] = 512 + wv * 32 + 16;
    chn[0] = 0; chn[1] = 0; chn[2] = 2; chn[3] = 2;
  } else {
    int u = wv - 8;
    Fb[0] = 256 + u * 64;      Fb[1] = 256 + u * 64 + 16;
    Fb[2] = 256 + u * 64 + 32; Fb[3] = 256 + u * 64 + 48;
    chn[0] = 1; chn[1] = 1; chn[2] = 1; chn[3] = 1;
  }

  const int laneB = l15 * 64 + hi * 16;
  const char* blobc = (const char*)blob + laneB;
  const int rotk = ROT ? (Sid * 3 + wv) % 10 : 0;

  if (wv < 8)
    gemm4<2, 2, 4, 4, BD>(X, blobc + Fb[0] * 64, blobc + Fb[1] * 64,
                             blobc + Fb[2] * 64, blobc + Fb[3] * 64,
                             l15, hi, rotk, acc);
  else
    gemm4<3, 3, 3, 3, BD>(X, blobc + Fb[0] * 64, blobc + Fb[1] * 64,
                             blobc + Fb[2] * 64, blobc + Fb[3] * 64,
                             l15, hi, rotk, acc);

  // epilogue: maxpool(valid p) -> +bias -> relu -> norm SS + patch scatter
  float ss = 0.f;
  const int b = Sid >> 9, c = Sid & 511;
  #pragma unroll
  for (int n = 0; n < 4; n++) {
    int ch = chn[n];
    int F  = Fb[n] + l15;
    int plim = 39 - ch;                          // valid p: p < 41-k, k=ch+2
    float vmax = -1e30f;
    #pragma unroll
    for (int m = 0; m < 3; m++) {
      #pragma unroll
      for (int rg = 0; rg < 4; rg++) {
        int p = 16 * m + 4 * hi + rg;
        if (p < plim) vmax = fmaxf(vmax, acc[n][m][rg]);
      }
    }
    vmax = fmaxf(vmax, __shfl_xor(vmax, 16, 64));
    vmax = fmaxf(vmax, __shfl_xor(vmax, 32, 64));
    const float* bias = (ch == 0) ? b2 : (ch == 1 ? b3 : b4);
    float val = fmaxf(vmax + bias[F & 255], 0.f);
    if (hi == 0) {
      float mult = (c == 511) ? 65.f : 1.f;
      ss += mult * val * val;                    // norm uses pre-clip img
      float st = fminf(val, 1.f);                // clamp to [0,1]; val>=0
      int fi = F & 255;
      int pi = fi >> 4, pj = fi & 15;
      if (c < 511) {
        int pr = c / 24, pc = c - pr * 24;
        out[((size_t)(b * 3 + ch) * IMGE + pr * 16 + pi) * IMGE + pc * 16 + pj] = st;
      } else {
        for (int pidx = 511; pidx < 576; pidx++) {
          int pr = pidx / 24, pc = pidx - pr * 24;
          out[((size_t)(b * 3 + ch) * IMGE + pr * 16 + pi) * IMGE + pc * 16 + pj] = st;
        }
      }
    }
  }
  #pragma unroll
  for (int off = 32; off; off >>= 1) ss += __shfl_xor(ss, off, 64);
  if (l == 0) wss[wv] = ss;
  __syncthreads();
  if (tid == 0) {
    float tt = 0.f;
    #pragma unroll
    for (int i = 0; i < 12; i++) tt += wss[i];
    atomicAdd(nrm, tt);
  }
}

__global__ void finalize(const float* __restrict__ nrm, float* __restrict__ out) {
  if (threadIdx.x == 0) out[3538944] = sqrtf(nrm[0]) * 0.125f;
}

extern "C" void kernel_launch(void* const* d_in, const int* in_sizes, int n_in,
                              void* d_out, int out_size, void* d_ws, size_t ws_size,
                              hipStream_t stream)
{
  const int*   sb = (const int*)d_in[0];
  const float* W  = (const float*)d_in[1];
  const float* w2 = (const float*)d_in[2];
  const float* b2 = (const float*)d_in[3];
  const float* w3 = (const float*)d_in[4];
  const float* b3 = (const float*)d_in[5];
  const float* w4 = (const float*)d_in[6];
  const float* b4 = (const float*)d_in[7];
  float* out = (float*)d_out;
  float* nrm = (float*)d_ws;
  unsigned short* blob = (unsigned short*)((char*)d_ws + BLOB_OFF);

  hipMemsetAsync(d_ws, 0, 8, stream);                       // norm accumulator
  prep_weights<<<dim3(40, 12), 256, 0, stream>>>(w2, w3, w4, blob);
  // within-probe 3-way ablation over sentence thirds:
  //   V0: depth-1, no rot (R5 replica)  V1: depth-3  V2: depth-3 + rot
  main_conv_t<1, false><<<1366, 768, 0, stream>>>(sb, W, b2, b3, b4, blob, out, nrm, 0);
  main_conv_t<3, false><<<1365, 768, 0, stream>>>(sb, W, b2, b3, b4, blob, out, nrm, 1366);
  main_conv_t<3, true ><<<1365, 768, 0, stream>>>(sb, W, b2, b3, b4, blob, out, nrm, 2731);
  finalize<<<1, 64, 0, stream>>>(nrm, out);
}

// Round 15
// 577.393 us; speedup vs baseline: 1.1098x; 1.1098x over previous
//
#include <hip/hip_runtime.h>
#include <hip/hip_bf16.h>
#include <cstdint>

// Problem constants
#define IMGE    384
#define XROWS   51              // LDS rows (need up to row 50 = 16*2+15+3)
#define XROWB   (XROWS * 640)   // 32640 bytes (320 bf16 cols, 640 B/row)
#define BLOB_OFF 256

using bf16x8 = short  __attribute__((ext_vector_type(8)));
using f32x4  = float  __attribute__((ext_vector_type(4)));

__device__ __forceinline__ unsigned int f2bf(float f) {
  unsigned int u = __builtin_bit_cast(unsigned int, f);
  u += 0x7FFFu + ((u >> 16) & 1u);          // round-to-nearest-even
  return u >> 16;
}

#define MF(a, b, c) __builtin_amdgcn_mfma_f32_16x16x32_bf16(a, b, c, 0, 0, 0)

// ---------------------------------------------------------------------------
// Prep: repack conv weights (fp32, [256][1][k][300]) into bf16 fragment-order
// blob: byte = ((kappa*768 + F)*32 + e')*2, kappa = j*10+kk, e = kk*32+e'.
// ---------------------------------------------------------------------------
__global__ __launch_bounds__(256) void prep_weights(
    const float* __restrict__ w2, const float* __restrict__ w3,
    const float* __restrict__ w4, unsigned short* __restrict__ blob)
{
  int kappa = blockIdx.x;                       // 0..39
  int fq = blockIdx.y * 256 + threadIdx.x;      // F*4 + q, 0..3071
  int F = fq >> 2;
  int q = fq & 3;
  int j = kappa / 10, kk = kappa - 10 * j;
  int ch = F >> 8, f = F & 255;
  int k = ch + 2;
  const float* w = (ch == 0) ? w2 : (ch == 1 ? w3 : w4);

  bf16x8 pv;
  if (j < k) {
    const float* src = w + (size_t)(f * k + j) * 300;
    #pragma unroll
    for (int i = 0; i < 8; i++) {
      int e = kk * 32 + q * 8 + i;
      pv[i] = (e < 300) ? (short)f2bf(src[e]) : (short)0;
    }
  } else {
    #pragma unroll
    for (int i = 0; i < 8; i++) pv[i] = 0;
  }
  unsigned short* dst = blob + (size_t)(kappa * 768 + F) * 32 + q * 8;
  *(bf16x8*)dst = pv;
}

// ---------------------------------------------------------------------------
// V0 GEMM: fully-unrolled (R5/R13-V0 anchor), depth-1 B prefetch.
// ---------------------------------------------------------------------------
template<int K0, int K1, int K2, int K3>
__device__ __forceinline__ void gemm_unrolled(
    const char* Xs, const char* bb0, const char* bb1,
    const char* bb2, const char* bb3,
    int l15, int hi, f32x4 (&acc)[4][3])
{
  constexpr int KA = K0 > K1 ? K0 : K1;
  constexpr int KB = K2 > K3 ? K2 : K3;
  constexpr int KM = KA > KB ? KA : KB;
  constexpr int T  = KM * 10;

  bf16x8 Ap[2][3];
  bf16x8 Bp[4][4];
  const int hx = (hi * 16);

#define ISSUE_A(TT, SL) {                                                \
    const int j_ = (TT) / 10, kk_ = (TT) - 10 * ((TT) / 10);             \
    _Pragma("unroll")                                                    \
    for (int m_ = 0; m_ < 3; m_++) {                                     \
      int row_ = m_ * 16 + l15 + j_;                                     \
      int cc_  = (kk_ * 64 + hx) ^ ((row_ & 7) << 4);                    \
      Ap[SL][m_] = *(const bf16x8*)(Xs + (row_ * 640 + cc_));            \
    } }

#define ISSUE_B(TT, SL) {                                                \
    const int j_ = (TT) / 10, kk_ = (TT) - 10 * ((TT) / 10);             \
    const int ko_ = (j_ * 10 + kk_) * 49152;                             \
    if (j_ < K0) Bp[SL][0] = *(const bf16x8*)(bb0 + ko_);                \
    if (j_ < K1) Bp[SL][1] = *(const bf16x8*)(bb1 + ko_);                \
    if (j_ < K2) Bp[SL][2] = *(const bf16x8*)(bb2 + ko_);                \
    if (j_ < K3) Bp[SL][3] = *(const bf16x8*)(bb3 + ko_); }

  ISSUE_A(0, 0)
  ISSUE_B(0, 0)

  #pragma unroll
  for (int t = 0; t < T; ++t) {
    const int j = t / 10;
    if (t + 1 < T) { ISSUE_A(t + 1, (t + 1) & 1) ISSUE_B(t + 1, (t + 1) & 3) }
    __builtin_amdgcn_s_setprio(1);
    {
      const int sa = t & 1, sbt = t & 3;
      if (j < K0) { acc[0][0] = MF(Ap[sa][0], Bp[sbt][0], acc[0][0]);
                    acc[0][1] = MF(Ap[sa][1], Bp[sbt][0], acc[0][1]);
                    acc[0][2] = MF(Ap[sa][2], Bp[sbt][0], acc[0][2]); }
      if (j < K1) { acc[1][0] = MF(Ap[sa][0], Bp[sbt][1], acc[1][0]);
                    acc[1][1] = MF(Ap[sa][1], Bp[sbt][1], acc[1][1]);
                    acc[1][2] = MF(Ap[sa][2], Bp[sbt][1], acc[1][2]); }
      if (j < K2) { acc[2][0] = MF(Ap[sa][0], Bp[sbt][2], acc[2][0]);
                    acc[2][1] = MF(Ap[sa][1], Bp[sbt][2], acc[2][1]);
                    acc[2][2] = MF(Ap[sa][2], Bp[sbt][2], acc[2][2]); }
      if (j < K3) { acc[3][0] = MF(Ap[sa][0], Bp[sbt][3], acc[3][0]);
                    acc[3][1] = MF(Ap[sa][1], Bp[sbt][3], acc[3][1]);
                    acc[3][2] = MF(Ap[sa][2], Bp[sbt][3], acc[3][2]); }
    }
    __builtin_amdgcn_s_setprio(0);
  }
#undef ISSUE_A
#undef ISSUE_B
}

// ---------------------------------------------------------------------------
// V1 GEMM: ROLLED kk-loop (I-cache hypothesis). Same math; ~1KB/j of code,
// one shared path for both wave classes (runtime K01/K23), 2-stage register
// pipeline (P/Q named sets), issue-before-MFMA ordering.
// ---------------------------------------------------------------------------
__device__ __forceinline__ void gemm_rolled(
    const char* __restrict__ Xs, const char* __restrict__ blob,
    int vo0, int vo1, int vo2, int vo3,
    int l15, int hi, int K01, int K23, f32x4 (&acc)[4][3])
{
  const int hx = hi * 16;
  const int Kmax = (K01 > K23) ? K01 : K23;
  #pragma unroll 1
  for (int j = 0; j < 4; ++j) {
    if (j >= Kmax) break;
    const bool a01 = (j < K01);
    const bool a23 = (j < K23);
    const int rx  = ((l15 + j) & 7) << 4;     // 16m doesn't affect &7
    const int rb0 = (l15 + j) * 640;
    const int rb1 = rb0 + 10240;
    const int rb2 = rb0 + 20480;
    const int koj = j * 491520;               // j*10*49152

    bf16x8 pa0, pa1, pa2, pb0, pb1, pb2, pb3;
    bf16x8 qa0, qa1, qa2, qb0, qb1, qb2, qb3;
    {
      const int cc = hx ^ rx;                 // kk = 0
      pa0 = *(const bf16x8*)(Xs + rb0 + cc);
      pa1 = *(const bf16x8*)(Xs + rb1 + cc);
      pa2 = *(const bf16x8*)(Xs + rb2 + cc);
      if (a01) { pb0 = *(const bf16x8*)(blob + (vo0 + koj));
                 pb1 = *(const bf16x8*)(blob + (vo1 + koj)); }
      if (a23) { pb2 = *(const bf16x8*)(blob + (vo2 + koj));
                 pb3 = *(const bf16x8*)(blob + (vo3 + koj)); }
    }
    #pragma unroll 1
    for (int kk = 0; kk < 10; kk += 2) {
      {                                       // issue kk+1 -> Q
        const int cc = (((kk + 1) << 6) + hx) ^ rx;
        const int ko = koj + (kk + 1) * 49152;
        qa0 = *(const bf16x8*)(Xs + rb0 + cc);
        qa1 = *(const bf16x8*)(Xs + rb1 + cc);
        qa2 = *(const bf16x8*)(Xs + rb2 + cc);
        if (a01) { qb0 = *(const bf16x8*)(blob + (vo0 + ko));
                   qb1 = *(const bf16x8*)(blob + (vo1 + ko)); }
        if (a23) { qb2 = *(const bf16x8*)(blob + (vo2 + ko));
                   qb3 = *(const bf16x8*)(blob + (vo3 + ko)); }
      }
      __builtin_amdgcn_s_setprio(1);
      if (a01) { acc[0][0] = MF(pa0, pb0, acc[0][0]); acc[0][1] = MF(pa1, pb0, acc[0][1]); acc[0][2] = MF(pa2, pb0, acc[0][2]);
                 acc[1][0] = MF(pa0, pb1, acc[1][0]); acc[1][1] = MF(pa1, pb1, acc[1][1]); acc[1][2] = MF(pa2, pb1, acc[1][2]); }
      if (a23) { acc[2][0] = MF(pa0, pb2, acc[2][0]); acc[2][1] = MF(pa1, pb2, acc[2][1]); acc[2][2] = MF(pa2, pb2, acc[2][2]);
                 acc[3][0] = MF(pa0, pb3, acc[3][0]); acc[3][1] = MF(pa1, pb3, acc[3][1]); acc[3][2] = MF(pa2, pb3, acc[3][2]); }
      __builtin_amdgcn_s_setprio(0);
      if (kk + 2 < 10) {                      // issue kk+2 -> P (uniform branch)
        const int cc = (((kk + 2) << 6) + hx) ^ rx;
        const int ko = koj + (kk + 2) * 49152;
        pa0 = *(const bf16x8*)(Xs + rb0 + cc);
        pa1 = *(const bf16x8*)(Xs + rb1 + cc);
        pa2 = *(const bf16x8*)(Xs + rb2 + cc);
        if (a01) { pb0 = *(const bf16x8*)(blob + (vo0 + ko));
                   pb1 = *(const bf16x8*)(blob + (vo1 + ko)); }
        if (a23) { pb2 = *(const bf16x8*)(blob + (vo2 + ko));
                   pb3 = *(const bf16x8*)(blob + (vo3 + ko)); }
      }
      __builtin_amdgcn_s_setprio(1);
      if (a01) { acc[0][0] = MF(qa0, qb0, acc[0][0]); acc[0][1] = MF(qa1, qb0, acc[0][1]); acc[0][2] = MF(qa2, qb0, acc[0][2]);
                 acc[1][0] = MF(qa0, qb1, acc[1][0]); acc[1][1] = MF(qa1, qb1, acc[1][1]); acc[1][2] = MF(qa2, qb1, acc[1][2]); }
      if (a23) { acc[2][0] = MF(qa0, qb2, acc[2][0]); acc[2][1] = MF(qa1, qb2, acc[2][1]); acc[2][2] = MF(qa2, qb2, acc[2][2]);
                 acc[3][0] = MF(qa0, qb3, acc[3][0]); acc[3][1] = MF(qa1, qb3, acc[3][1]); acc[3][2] = MF(qa2, qb3, acc[3][2]); }
      __builtin_amdgcn_s_setprio(0);
    }
  }
}

// ---------------------------------------------------------------------------
// Shared kernel body: prologue (zero + gather), tile map, epilogue.
// ROLLED selects the gemm implementation.
// ---------------------------------------------------------------------------
template<bool ROLLED>
__global__ __launch_bounds__(768, 3) void main_conv_t(
    const int*  __restrict__ sb,   const float* __restrict__ W,
    const float* __restrict__ b2,  const float* __restrict__ b3,
    const float* __restrict__ b4,  const unsigned short* __restrict__ blob,
    float* __restrict__ out, float* __restrict__ nrm, int sidBase)
{
  __shared__ __align__(128) char X[XROWB];      // 32640 B
  __shared__ float wss[12];
  const int tid = threadIdx.x;
  const int wv  = tid >> 6;                     // 0..11
  const int l   = tid & 63;
  const int l15 = l & 15;
  const int hi  = l >> 4;
  const int Sid = sidBase + blockIdx.x;

  for (int off = tid * 16; off < XROWB; off += 768 * 16)
    *(f32x4*)(X + off) = f32x4{0.f, 0.f, 0.f, 0.f};
  __syncthreads();

  for (int idx = tid; idx < 3000; idx += 768) {
    int r  = idx / 75;
    int c4 = idx - r * 75;
    int tok = sb[Sid * 40 + r];
    float4 wvv = *(const float4*)(W + (size_t)tok * 300 + c4 * 4);
    uint2 pk;
    pk.x = f2bf(wvv.x) | (f2bf(wvv.y) << 16);
    pk.y = f2bf(wvv.z) | (f2bf(wvv.w) << 16);
    int off = r * 640 + ((c4 * 8) ^ ((r & 7) << 4));
    *(uint2*)(X + off) = pk;
  }
  __syncthreads();

  f32x4 acc[4][3];
  #pragma unroll
  for (int n = 0; n < 4; n++)
    #pragma unroll
    for (int m = 0; m < 3; m++)
      acc[n][m] = f32x4{0.f, 0.f, 0.f, 0.f};

  int Fb[4], chn[4];
  if (wv < 8) {
    Fb[0] = wv * 32;       Fb[1] = wv * 32 + 16;
    Fb[2] = 512 + wv * 32; Fb[3] = 512 + wv * 32 + 16;
    chn[0] = 0; chn[1] = 0; chn[2] = 2; chn[3] = 2;
  } else {
    int u = wv - 8;
    Fb[0] = 256 + u * 64;      Fb[1] = 256 + u * 64 + 16;
    Fb[2] = 256 + u * 64 + 32; Fb[3] = 256 + u * 64 + 48;
    chn[0] = 1; chn[1] = 1; chn[2] = 1; chn[3] = 1;
  }

  const int laneB = l15 * 64 + hi * 16;

  if (ROLLED) {
    const int K01 = (wv < 8) ? 2 : 3;
    const int K23 = (wv < 8) ? 4 : 3;
    gemm_rolled(X, (const char*)blob,
                laneB + Fb[0] * 64, laneB + Fb[1] * 64,
                laneB + Fb[2] * 64, laneB + Fb[3] * 64,
                l15, hi, K01, K23, acc);
  } else {
    const char* blobc = (const char*)blob + laneB;
    if (wv < 8)
      gemm_unrolled<2, 2, 4, 4>(X, blobc + Fb[0] * 64, blobc + Fb[1] * 64,
                                   blobc + Fb[2] * 64, blobc + Fb[3] * 64,
                                   l15, hi, acc);
    else
      gemm_unrolled<3, 3, 3, 3>(X, blobc + Fb[0] * 64, blobc + Fb[1] * 64,
                                   blobc + Fb[2] * 64, blobc + Fb[3] * 64,
                                   l15, hi, acc);
  }

  // epilogue: maxpool(valid p) -> +bias -> relu -> norm SS + patch scatter
  float ss = 0.f;
  const int b = Sid >> 9, c = Sid & 511;
  #pragma unroll
  for (int n = 0; n < 4; n++) {
    int ch = chn[n];
    int F  = Fb[n] + l15;
    int plim = 39 - ch;                          // valid p: p < 41-k, k=ch+2
    float vmax = -1e30f;
    #pragma unroll
    for (int m = 0; m < 3; m++) {
      #pragma unroll
      for (int rg = 0; rg < 4; rg++) {
        int p = 16 * m + 4 * hi + rg;
        if (p < plim) vmax = fmaxf(vmax, acc[n][m][rg]);
      }
    }
    vmax = fmaxf(vmax, __shfl_xor(vmax, 16, 64));
    vmax = fmaxf(vmax, __shfl_xor(vmax, 32, 64));
    const float* bias = (ch == 0) ? b2 : (ch == 1 ? b3 : b4);
    float val = fmaxf(vmax + bias[F & 255], 0.f);
    if (hi == 0) {
      float mult = (c == 511) ? 65.f : 1.f;
      ss += mult * val * val;                    // norm uses pre-clip img
      float st = fminf(val, 1.f);                // clamp to [0,1]; val>=0
      int fi = F & 255;
      int pi = fi >> 4, pj = fi & 15;
      if (c < 511) {
        int pr = c / 24, pc = c - pr * 24;
        out[((size_t)(b * 3 + ch) * IMGE + pr * 16 + pi) * IMGE + pc * 16 + pj] = st;
      } else {
        for (int pidx = 511; pidx < 576; pidx++) {
          int pr = pidx / 24, pc = pidx - pr * 24;
          out[((size_t)(b * 3 + ch) * IMGE + pr * 16 + pi) * IMGE + pc * 16 + pj] = st;
        }
      }
    }
  }
  #pragma unroll
  for (int off = 32; off; off >>= 1) ss += __shfl_xor(ss, off, 64);
  if (l == 0) wss[wv] = ss;
  __syncthreads();
  if (tid == 0) {
    float tt = 0.f;
    #pragma unroll
    for (int i = 0; i < 12; i++) tt += wss[i];
    atomicAdd(nrm, tt);
  }
}

__global__ void finalize(const float* __restrict__ nrm, float* __restrict__ out) {
  if (threadIdx.x == 0) out[3538944] = sqrtf(nrm[0]) * 0.125f;
}

extern "C" void kernel_launch(void* const* d_in, const int* in_sizes, int n_in,
                              void* d_out, int out_size, void* d_ws, size_t ws_size,
                              hipStream_t stream)
{
  const int*   sb = (const int*)d_in[0];
  const float* W  = (const float*)d_in[1];
  const float* w2 = (const float*)d_in[2];
  const float* b2 = (const float*)d_in[3];
  const float* w3 = (const float*)d_in[4];
  const float* b3 = (const float*)d_in[5];
  const float* w4 = (const float*)d_in[6];
  const float* b4 = (const float*)d_in[7];
  float* out = (float*)d_out;
  float* nrm = (float*)d_ws;
  unsigned short* blob = (unsigned short*)((char*)d_ws + BLOB_OFF);

  hipMemsetAsync(d_ws, 0, 8, stream);                       // norm accumulator
  prep_weights<<<dim3(40, 12), 256, 0, stream>>>(w2, w3, w4, blob);
  // within-probe A/B over sentence halves:
  //   V0: fully-unrolled GEMM (R5 anchor)   V1: rolled kk-loop (I$ hypothesis)
  main_conv_t<false><<<2048, 768, 0, stream>>>(sb, W, b2, b3, b4, blob, out, nrm, 0);
  main_conv_t<true ><<<2048, 768, 0, stream>>>(sb, W, b2, b3, b4, blob, out, nrm, 2048);
  finalize<<<1, 64, 0, stream>>>(nrm, out);
}